// Round 1
// baseline (271.259 us; speedup 1.0000x reference)
//
#include <hip/hip_runtime.h>
#include <math.h>

#define B_ 2
#define L_ 2048
#define H_ 16
#define E_ 64
#define D_ 64
#define DM_ 512
#define DH_ 256

typedef __bf16 bf16_t;
typedef bf16_t bf16x8_t __attribute__((ext_vector_type(8)));
typedef bf16_t bf16x4_t __attribute__((ext_vector_type(4)));
typedef float f32x4_t __attribute__((ext_vector_type(4)));

__device__ __forceinline__ bf16_t to_bf16(float f) {
    union { float f; unsigned u; } x; x.f = f;
    unsigned r = (x.u + 0x7fffu + ((x.u >> 16) & 1u)) >> 16;
    union { unsigned short s; bf16_t b; } y; y.s = (unsigned short)r;
    return y.b;
}

// ---------------- MLP fusion: fused[b*L+l] = relu(raw@w1+b1)@w2 + b2 ----------
// 512 blocks x 128 threads; 8 positions per block.
__global__ __launch_bounds__(128) void mlp_kernel(
        const float* __restrict__ raw, const float* __restrict__ w1,
        const float* __restrict__ b1, const float* __restrict__ w2,
        const float* __restrict__ b2, float* __restrict__ fused) {
    __shared__ float sr[8][DM_];
    const int t = threadIdx.x;
    const int p0 = blockIdx.x * 8;
    // stage 8 raw rows (4096 floats = 1024 float4)
    #pragma unroll
    for (int u = 0; u < 8; ++u) {
        int idx = t + u * 128;          // float4 index
        int p = idx >> 7;               // 128 float4 per row
        int c = (idx & 127) << 2;
        *(f32x4_t*)&sr[p][c] = *(const f32x4_t*)&raw[(size_t)(p0 + p) * DM_ + c];
    }
    __syncthreads();
    const int jq = t & 63;
    const int j0 = jq << 2;            // 4 hidden units per lane, float4 on w1
    const int ty = t >> 6;             // wave id: splits positions 4+4
    float acc[4][4];
    #pragma unroll
    for (int p = 0; p < 4; ++p)
        #pragma unroll
        for (int k = 0; k < 4; ++k) acc[p][k] = 0.f;
    for (int i = 0; i < DM_; ++i) {
        f32x4_t w = *(const f32x4_t*)&w1[i * DH_ + j0];
        #pragma unroll
        for (int p = 0; p < 4; ++p) {
            float rv = sr[ty * 4 + p][i];   // LDS broadcast (wave-uniform)
            acc[p][0] += rv * w[0];
            acc[p][1] += rv * w[1];
            acc[p][2] += rv * w[2];
            acc[p][3] += rv * w[3];
        }
    }
    f32x4_t b1v = *(const f32x4_t*)&b1[j0];
    f32x4_t w2v = *(const f32x4_t*)&w2[j0];
    float b2v = b2[0];
    #pragma unroll
    for (int p = 0; p < 4; ++p) {
        float local = 0.f;
        #pragma unroll
        for (int k = 0; k < 4; ++k) {
            float hv = acc[p][k] + b1v[k];
            hv = hv > 0.f ? hv : 0.f;
            local += hv * w2v[k];
        }
        #pragma unroll
        for (int off = 32; off >= 1; off >>= 1)
            local += __shfl_xor(local, off);
        if (jq == 0) fused[p0 + ty * 4 + p] = local + b2v;
    }
}

// ---------------- momentum: mom[b,l] = l? fused[b,l]-fused[b,l-1] : 0 ---------
__global__ __launch_bounds__(256) void momentum_kernel(
        const float* __restrict__ fused, float* __restrict__ mom) {
    int i = blockIdx.x * 256 + threadIdx.x;
    if (i < B_ * L_) {
        int l = i & (L_ - 1);
        mom[i] = (l == 0) ? 0.f : fused[i] - fused[i - 1];
    }
}

// ---------------- flash attention with momentum bias, bf16 MFMA ---------------
// grid = B*H*(L/64) = 1024 blocks, 256 threads (4 waves x 16 q-rows).
__global__ __launch_bounds__(256) void attn_kernel(
        const float* __restrict__ Q, const float* __restrict__ K,
        const float* __restrict__ V, const float* __restrict__ mom,
        const float* __restrict__ alpha_trend, float* __restrict__ out) {
    __shared__ bf16_t Ks[64][72];      // [s][e], stride 72 bf16 (144 B)
    __shared__ bf16_t Vt[64][72];      // [d][s] transposed
    __shared__ bf16_t Ps[4][16][72];   // per-wave P scratch [q][s]
    __shared__ float  moms[64];

    const int bid  = blockIdx.x;
    const int bh   = bid & 31;             // b*16+h
    const int qt   = 31 - (bid >> 5);      // heavy diagonals first
    const int h    = bh & 15;
    const int b    = bh >> 4;
    const int q0   = qt << 6;
    const int tid  = threadIdx.x;
    const int wave = tid >> 6;
    const int lane = tid & 63;
    const int lrow = lane & 15;
    const int lgrp = lane >> 4;

    const float scale  = 0.125f;           // 1/sqrt(64)
    const float ascale = alpha_trend[h] * scale;
    const size_t bl    = (size_t)b * L_;
    const int qw0      = q0 + wave * 16;   // this wave's 16 q rows

    // Q fragments in registers for whole block lifetime.
    bf16x8_t a_lo, a_hi;
    {
        const float* qp = Q + ((bl + qw0 + lrow) * H_ + h) * E_ + lgrp * 8;
        f32x4_t v0 = *(const f32x4_t*)(qp);
        f32x4_t v1 = *(const f32x4_t*)(qp + 4);
        f32x4_t v2 = *(const f32x4_t*)(qp + 32);
        f32x4_t v3 = *(const f32x4_t*)(qp + 36);
        #pragma unroll
        for (int k = 0; k < 4; ++k) {
            a_lo[k]     = to_bf16(v0[k]);
            a_lo[4 + k] = to_bf16(v1[k]);
            a_hi[k]     = to_bf16(v2[k]);
            a_hi[4 + k] = to_bf16(v3[k]);
        }
    }
    float mq[4];
    #pragma unroll
    for (int r = 0; r < 4; ++r) mq[r] = mom[bl + qw0 + lgrp * 4 + r];

    f32x4_t Oacc[4];
    #pragma unroll
    for (int c = 0; c < 4; ++c) Oacc[c] = (f32x4_t){0.f, 0.f, 0.f, 0.f};
    float m_i[4], l_i[4];
    #pragma unroll
    for (int r = 0; r < 4; ++r) { m_i[r] = -1e30f; l_i[r] = 0.f; }

    for (int st = 0; st <= qt; ++st) {
        const int s0 = st << 6;
        __syncthreads();   // previous PV readers done before restage
        // stage K (bf16) and V^T (bf16)
        #pragma unroll
        for (int u = 0; u < 4; ++u) {
            int idx = tid + (u << 8);
            int row = idx >> 4;
            int e0  = (idx & 15) << 2;
            f32x4_t kv = *(const f32x4_t*)&K[((bl + s0 + row) * H_ + h) * E_ + e0];
            bf16x4_t kb;
            #pragma unroll
            for (int k = 0; k < 4; ++k) kb[k] = to_bf16(kv[k]);
            *(bf16x4_t*)&Ks[row][e0] = kb;
            f32x4_t vv = *(const f32x4_t*)&V[((bl + s0 + row) * H_ + h) * D_ + e0];
            #pragma unroll
            for (int k = 0; k < 4; ++k) Vt[e0 + k][row] = to_bf16(vv[k]);
        }
        if (tid < 64) moms[tid] = mom[bl + s0 + tid];
        __syncthreads();

        // S = Q K^T  (16q x 64s per wave, 4 n-chunks)
        f32x4_t Sacc[4];
        #pragma unroll
        for (int c = 0; c < 4; ++c) Sacc[c] = (f32x4_t){0.f, 0.f, 0.f, 0.f};
        #pragma unroll
        for (int c = 0; c < 4; ++c) {
            bf16x8_t b_lo = *(const bf16x8_t*)&Ks[c * 16 + lrow][lgrp * 8];
            bf16x8_t b_hi = *(const bf16x8_t*)&Ks[c * 16 + lrow][32 + lgrp * 8];
            Sacc[c] = __builtin_amdgcn_mfma_f32_16x16x32_bf16(a_lo, b_lo, Sacc[c], 0, 0, 0);
            Sacc[c] = __builtin_amdgcn_mfma_f32_16x16x32_bf16(a_hi, b_hi, Sacc[c], 0, 0, 0);
        }

        // bias + causal mask (C layout: col = c*16+lrow = s, row = lgrp*4+r = q)
        float pv[4][4];
        #pragma unroll
        for (int c = 0; c < 4; ++c) {
            float ms = moms[c * 16 + lrow];
            #pragma unroll
            for (int r = 0; r < 4; ++r)
                pv[c][r] = Sacc[c][r] * scale - ascale * fabsf(mq[r] - ms);
        }
        if (st == qt) {   // only the diagonal macro-tile needs masking
            #pragma unroll
            for (int c = 0; c < 4; ++c) {
                int sg = s0 + c * 16 + lrow;
                #pragma unroll
                for (int r = 0; r < 4; ++r) {
                    int qg = qw0 + lgrp * 4 + r;
                    if (sg > qg) pv[c][r] = -1e30f;
                }
            }
        }

        // online softmax per q row (reduce across 16 lanes = 64 s cols)
        #pragma unroll
        for (int r = 0; r < 4; ++r) {
            float rm = fmaxf(fmaxf(pv[0][r], pv[1][r]), fmaxf(pv[2][r], pv[3][r]));
            rm = fmaxf(rm, __shfl_xor(rm, 1));
            rm = fmaxf(rm, __shfl_xor(rm, 2));
            rm = fmaxf(rm, __shfl_xor(rm, 4));
            rm = fmaxf(rm, __shfl_xor(rm, 8));
            float mn   = fmaxf(m_i[r], rm);
            float corr = __expf(m_i[r] - mn);
            m_i[r] = mn;
            float rs = 0.f;
            #pragma unroll
            for (int c = 0; c < 4; ++c) {
                float e = __expf(pv[c][r] - mn);
                pv[c][r] = e;
                rs += e;
            }
            rs += __shfl_xor(rs, 1);
            rs += __shfl_xor(rs, 2);
            rs += __shfl_xor(rs, 4);
            rs += __shfl_xor(rs, 8);
            l_i[r] = l_i[r] * corr + rs;
            #pragma unroll
            for (int c = 0; c < 4; ++c) Oacc[c][r] *= corr;
        }

        // P -> LDS (C layout) so it can re-enter as an A-operand fragment
        #pragma unroll
        for (int c = 0; c < 4; ++c)
            #pragma unroll
            for (int r = 0; r < 4; ++r)
                Ps[wave][lgrp * 4 + r][c * 16 + lrow] = to_bf16(pv[c][r]);
        __syncthreads();

        // O += P V  (A = P[q][s], B = V[s][d] read from Vt[d][s])
        #pragma unroll
        for (int hh = 0; hh < 2; ++hh) {
            bf16x8_t ap = *(const bf16x8_t*)&Ps[wave][lrow][hh * 32 + lgrp * 8];
            #pragma unroll
            for (int c2 = 0; c2 < 4; ++c2) {
                bf16x8_t bv = *(const bf16x8_t*)&Vt[c2 * 16 + lrow][hh * 32 + lgrp * 8];
                Oacc[c2] = __builtin_amdgcn_mfma_f32_16x16x32_bf16(ap, bv, Oacc[c2], 0, 0, 0);
            }
        }
    }

    // epilogue: normalize and store (C layout -> [B,L,H,D])
    #pragma unroll
    for (int r = 0; r < 4; ++r) {
        float inv = 1.f / l_i[r];
        size_t orow = ((bl + qw0 + lgrp * 4 + r) * H_ + h) * D_;
        #pragma unroll
        for (int c = 0; c < 4; ++c)
            out[orow + c * 16 + lrow] = Oacc[c][r] * inv;
    }
}

extern "C" void kernel_launch(void* const* d_in, const int* in_sizes, int n_in,
                              void* d_out, int out_size, void* d_ws, size_t ws_size,
                              hipStream_t stream) {
    const float* Q     = (const float*)d_in[0];
    const float* K     = (const float*)d_in[1];
    const float* V     = (const float*)d_in[2];
    const float* raw   = (const float*)d_in[3];
    const float* w1    = (const float*)d_in[4];
    const float* b1    = (const float*)d_in[5];
    const float* w2    = (const float*)d_in[6];
    const float* b2    = (const float*)d_in[7];
    const float* alpha = (const float*)d_in[8];
    float* out = (float*)d_out;

    float* fused = (float*)d_ws;           // B*L floats
    float* mom   = fused + B_ * L_;        // B*L floats

    mlp_kernel<<<B_ * L_ / 8, 128, 0, stream>>>(raw, w1, b1, w2, b2, fused);
    momentum_kernel<<<(B_ * L_ + 255) / 256, 256, 0, stream>>>(fused, mom);
    attn_kernel<<<B_ * H_ * (L_ / 64), 256, 0, stream>>>(Q, K, V, mom, alpha, out);
}

// Round 2
// 248.016 us; speedup vs baseline: 1.0937x; 1.0937x over previous
//
#include <hip/hip_runtime.h>
#include <math.h>

#define B_ 2
#define L_ 2048
#define H_ 16
#define E_ 64
#define D_ 64
#define DM_ 512
#define DH_ 256

typedef __bf16 bf16_t;
typedef bf16_t bf16x8_t __attribute__((ext_vector_type(8)));
typedef float f32x4_t __attribute__((ext_vector_type(4)));

// pack two floats to bf16x2 (round-up-at-halfway; 2 add + 1 perm)
__device__ __forceinline__ unsigned bpack(float hi, float lo) {
    unsigned uh = __float_as_uint(hi) + 0x8000u;
    unsigned ul = __float_as_uint(lo) + 0x8000u;
    return __builtin_amdgcn_perm(uh, ul, 0x07060302u);
}

__device__ __forceinline__ bf16_t to_bf16(float f) {
    union { float f; unsigned u; } x; x.f = f;
    unsigned r = (x.u + 0x7fffu + ((x.u >> 16) & 1u)) >> 16;
    union { unsigned short s; bf16_t b; } y; y.s = (unsigned short)r;
    return y.b;
}

// ---------------- MLP fusion: fused[b*L+l] = relu(raw@w1+b1)@w2 + b2 ----------
// 512 blocks x 256 threads; 8 positions per block, 2 per wave-quarter.
__global__ __launch_bounds__(256) void mlp_kernel(
        const float* __restrict__ raw, const float* __restrict__ w1,
        const float* __restrict__ b1, const float* __restrict__ w2,
        const float* __restrict__ b2, float* __restrict__ fused) {
    __shared__ float sr[8][DM_];
    const int t = threadIdx.x;
    const int p0 = blockIdx.x * 8;
    #pragma unroll
    for (int u = 0; u < 4; ++u) {
        int idx = t + u * 256;          // float4 index
        int p = idx >> 7;               // 128 float4 per row
        int c = (idx & 127) << 2;
        *(f32x4_t*)&sr[p][c] = *(const f32x4_t*)&raw[(size_t)(p0 + p) * DM_ + c];
    }
    __syncthreads();
    const int jq = t & 63;
    const int j0 = jq << 2;            // 4 hidden units per lane (covers 256)
    const int pg = t >> 6;             // wave id -> positions pg*2, pg*2+1
    float acc[2][4];
    #pragma unroll
    for (int p = 0; p < 2; ++p)
        #pragma unroll
        for (int k = 0; k < 4; ++k) acc[p][k] = 0.f;
    for (int i4 = 0; i4 < DM_; i4 += 4) {
        f32x4_t w0 = *(const f32x4_t*)&w1[(i4 + 0) * DH_ + j0];
        f32x4_t w1v = *(const f32x4_t*)&w1[(i4 + 1) * DH_ + j0];
        f32x4_t w2v_ = *(const f32x4_t*)&w1[(i4 + 2) * DH_ + j0];
        f32x4_t w3 = *(const f32x4_t*)&w1[(i4 + 3) * DH_ + j0];
        f32x4_t r0 = *(const f32x4_t*)&sr[pg * 2][i4];
        f32x4_t r1 = *(const f32x4_t*)&sr[pg * 2 + 1][i4];
        #pragma unroll
        for (int j = 0; j < 4; ++j) {
            acc[0][j] += r0[0] * w0[j] + r0[1] * w1v[j] + r0[2] * w2v_[j] + r0[3] * w3[j];
            acc[1][j] += r1[0] * w0[j] + r1[1] * w1v[j] + r1[2] * w2v_[j] + r1[3] * w3[j];
        }
    }
    f32x4_t b1v = *(const f32x4_t*)&b1[j0];
    f32x4_t w2v = *(const f32x4_t*)&w2[j0];
    float b2v = b2[0];
    #pragma unroll
    for (int p = 0; p < 2; ++p) {
        float local = 0.f;
        #pragma unroll
        for (int k = 0; k < 4; ++k) {
            float hv = acc[p][k] + b1v[k];
            hv = hv > 0.f ? hv : 0.f;
            local += hv * w2v[k];
        }
        #pragma unroll
        for (int off = 32; off >= 1; off >>= 1)
            local += __shfl_xor(local, off);
        if (jq == 0) fused[p0 + pg * 2 + p] = local + b2v;
    }
}

// ---------------- momentum ----------------------------------------------------
__global__ __launch_bounds__(256) void momentum_kernel(
        const float* __restrict__ fused, float* __restrict__ mom) {
    int i = blockIdx.x * 256 + threadIdx.x;
    if (i < B_ * L_) {
        int l = i & (L_ - 1);
        mom[i] = (l == 0) ? 0.f : fused[i] - fused[i - 1];
    }
}

// ---------------- flash attention, no-max softmax, pipelined staging ----------
struct TileRegs { f32x4_t k[4]; float v[16]; float m; };

__global__ __launch_bounds__(256) void attn_kernel(
        const float* __restrict__ Q, const float* __restrict__ K,
        const float* __restrict__ V, const float* __restrict__ mom,
        const float* __restrict__ alpha_trend, float* __restrict__ out) {
    __shared__ bf16_t Ks[64][72];           // [s][e]
    __shared__ bf16_t Vt[64][72];           // [d][s]
    __shared__ unsigned short Ps[4][16][68]; // per-wave P scratch [q][s], bf16 bits
    __shared__ float moms[64];

    const int bid  = blockIdx.x;
    const int bh   = bid & 31;
    const int qt   = 31 - (bid >> 5);       // heavy diagonals first
    const int h    = bh & 15;
    const int b    = bh >> 4;
    const int q0   = qt << 6;
    const int tid  = threadIdx.x;
    const int wave = tid >> 6;
    const int lane = tid & 63;
    const int lrow = lane & 15;
    const int lgrp = lane >> 4;

    const float c1     = 0.18033688f;       // 0.125 * log2(e)
    const float ascale2 = alpha_trend[h] * c1;
    const size_t bl    = (size_t)b * L_;
    const int qw0      = q0 + wave * 16;

    const float* Kb   = K + ((bl)*H_ + h) * E_;
    const float* Vb   = V + ((bl)*H_ + h) * D_;
    const float* momp = mom + bl;

    // staging thread mapping
    const int krow = tid >> 4;              // +u*16
    const int ke0  = (tid & 15) << 2;
    const int vd   = tid & 63;
    const int vsb  = tid >> 6;

    // Q fragments, prescaled by c1 (RNE, once)
    bf16x8_t a_lo, a_hi;
    {
        const float* qp = Q + ((bl + qw0 + lrow) * H_ + h) * E_ + lgrp * 8;
        f32x4_t v0 = *(const f32x4_t*)(qp);
        f32x4_t v1 = *(const f32x4_t*)(qp + 4);
        f32x4_t v2 = *(const f32x4_t*)(qp + 32);
        f32x4_t v3 = *(const f32x4_t*)(qp + 36);
        #pragma unroll
        for (int k = 0; k < 4; ++k) {
            a_lo[k]     = to_bf16(v0[k] * c1);
            a_lo[4 + k] = to_bf16(v1[k] * c1);
            a_hi[k]     = to_bf16(v2[k] * c1);
            a_hi[4 + k] = to_bf16(v3[k] * c1);
        }
    }
    float mq[4];
    #pragma unroll
    for (int r = 0; r < 4; ++r) mq[r] = momp[qw0 + lgrp * 4 + r];

    f32x4_t Oacc[4];
    #pragma unroll
    for (int c = 0; c < 4; ++c) Oacc[c] = (f32x4_t){0.f, 0.f, 0.f, 0.f};
    float rowsum[4] = {0.f, 0.f, 0.f, 0.f};

    // prologue: preload tile 0 into registers
    TileRegs tr;
    {
        #pragma unroll
        for (int u = 0; u < 4; ++u)
            tr.k[u] = *(const f32x4_t*)&Kb[(krow + u * 16) * (H_ * E_) + ke0];
        #pragma unroll
        for (int j = 0; j < 16; ++j)
            tr.v[j] = Vb[(vsb * 16 + j) * (H_ * D_) + vd];
        tr.m = (tid < 64) ? momp[tid] : 0.f;
    }

    for (int st = 0; st <= qt; ++st) {
        __syncthreads();   // previous compute done reading LDS
        // registers -> LDS (bf16 packed)
        #pragma unroll
        for (int u = 0; u < 4; ++u) {
            uint2 p;
            p.x = bpack(tr.k[u][1], tr.k[u][0]);
            p.y = bpack(tr.k[u][3], tr.k[u][2]);
            *(uint2*)&Ks[krow + u * 16][ke0] = p;
        }
        #pragma unroll
        for (int u = 0; u < 4; ++u) {
            uint2 p;
            p.x = bpack(tr.v[u * 4 + 1], tr.v[u * 4 + 0]);
            p.y = bpack(tr.v[u * 4 + 3], tr.v[u * 4 + 2]);
            *(uint2*)&Vt[vd][vsb * 16 + u * 4] = p;
        }
        if (tid < 64) moms[tid] = tr.m;
        __syncthreads();   // stage visible

        // issue next tile's global loads (latency hidden behind compute)
        if (st < qt) {
            const int s0n = (st + 1) << 6;
            #pragma unroll
            for (int u = 0; u < 4; ++u)
                tr.k[u] = *(const f32x4_t*)&Kb[(s0n + krow + u * 16) * (H_ * E_) + ke0];
            #pragma unroll
            for (int j = 0; j < 16; ++j)
                tr.v[j] = Vb[(s0n + vsb * 16 + j) * (H_ * D_) + vd];
            tr.m = (tid < 64) ? momp[s0n + tid] : 0.f;
        }

        // S = Q K^T (already in log2 domain via prescale)
        f32x4_t Sacc[4];
        #pragma unroll
        for (int c = 0; c < 4; ++c) Sacc[c] = (f32x4_t){0.f, 0.f, 0.f, 0.f};
        #pragma unroll
        for (int c = 0; c < 4; ++c) {
            bf16x8_t b_lo = *(const bf16x8_t*)&Ks[c * 16 + lrow][lgrp * 8];
            bf16x8_t b_hi = *(const bf16x8_t*)&Ks[c * 16 + lrow][32 + lgrp * 8];
            Sacc[c] = __builtin_amdgcn_mfma_f32_16x16x32_bf16(a_lo, b_lo, Sacc[c], 0, 0, 0);
            Sacc[c] = __builtin_amdgcn_mfma_f32_16x16x32_bf16(a_hi, b_hi, Sacc[c], 0, 0, 0);
        }

        // P = exp2(S - ascale2*|dm|), no max subtraction needed
        float rowe[4][4];
        #pragma unroll
        for (int c = 0; c < 4; ++c) {
            float ms = moms[c * 16 + lrow];
            #pragma unroll
            for (int r = 0; r < 4; ++r) {
                float arg = Sacc[c][r] - ascale2 * fabsf(mq[r] - ms);
                rowe[c][r] = __builtin_amdgcn_exp2f(arg);
            }
        }
        if (st == qt) {   // causal mask on diagonal macro-tile
            const int s0 = st << 6;
            #pragma unroll
            for (int c = 0; c < 4; ++c) {
                int sg = s0 + c * 16 + lrow;
                #pragma unroll
                for (int r = 0; r < 4; ++r)
                    if (sg > qw0 + lgrp * 4 + r) rowe[c][r] = 0.f;
            }
        }
        // store bf16 P (wave-private scratch; no barrier needed) + row sums
        unsigned short* Psw = &Ps[wave][0][0];
        #pragma unroll
        for (int c = 0; c < 4; ++c) {
            #pragma unroll
            for (int r = 0; r < 4; ++r) {
                unsigned u = (__float_as_uint(rowe[c][r]) + 0x8000u) & 0xffff0000u;
                Psw[(lgrp * 4 + r) * 68 + c * 16 + lrow] = (unsigned short)(u >> 16);
                rowsum[r] += __uint_as_float(u);
            }
        }

        // O += P V
        #pragma unroll
        for (int hh = 0; hh < 2; ++hh) {
            union { uint2 u2[2]; bf16x8_t v; } ab;
            ab.u2[0] = *(const uint2*)&Psw[lrow * 68 + hh * 32 + lgrp * 8];
            ab.u2[1] = *(const uint2*)&Psw[lrow * 68 + hh * 32 + lgrp * 8 + 4];
            #pragma unroll
            for (int c2 = 0; c2 < 4; ++c2) {
                bf16x8_t bv = *(const bf16x8_t*)&Vt[c2 * 16 + lrow][hh * 32 + lgrp * 8];
                Oacc[c2] = __builtin_amdgcn_mfma_f32_16x16x32_bf16(ab.v, bv, Oacc[c2], 0, 0, 0);
            }
        }
    }

    // epilogue: reduce row sums across the 16 s-lanes, normalize, store
    #pragma unroll
    for (int r = 0; r < 4; ++r) {
        float rs = rowsum[r];
        rs += __shfl_xor(rs, 1);
        rs += __shfl_xor(rs, 2);
        rs += __shfl_xor(rs, 4);
        rs += __shfl_xor(rs, 8);
        float inv = 1.f / rs;
        size_t orow = ((bl + qw0 + lgrp * 4 + r) * H_ + h) * D_;
        #pragma unroll
        for (int c = 0; c < 4; ++c)
            out[orow + c * 16 + lrow] = Oacc[c][r] * inv;
    }
}

extern "C" void kernel_launch(void* const* d_in, const int* in_sizes, int n_in,
                              void* d_out, int out_size, void* d_ws, size_t ws_size,
                              hipStream_t stream) {
    const float* Q     = (const float*)d_in[0];
    const float* K     = (const float*)d_in[1];
    const float* V     = (const float*)d_in[2];
    const float* raw   = (const float*)d_in[3];
    const float* w1    = (const float*)d_in[4];
    const float* b1    = (const float*)d_in[5];
    const float* w2    = (const float*)d_in[6];
    const float* b2    = (const float*)d_in[7];
    const float* alpha = (const float*)d_in[8];
    float* out = (float*)d_out;

    float* fused = (float*)d_ws;           // B*L floats
    float* mom   = fused + B_ * L_;        // B*L floats

    mlp_kernel<<<B_ * L_ / 8, 256, 0, stream>>>(raw, w1, b1, w2, b2, fused);
    momentum_kernel<<<(B_ * L_ + 255) / 256, 256, 0, stream>>>(fused, mom);
    attn_kernel<<<B_ * H_ * (L_ / 64), 256, 0, stream>>>(Q, K, V, mom, alpha, out);
}

// Round 3
// 162.820 us; speedup vs baseline: 1.6660x; 1.5232x over previous
//
#include <hip/hip_runtime.h>
#include <math.h>

#define B_ 2
#define L_ 2048
#define H_ 16
#define E_ 64
#define D_ 64
#define DM_ 512
#define DH_ 256

typedef __bf16 bf16_t;
typedef bf16_t bf16x8_t __attribute__((ext_vector_type(8)));
typedef float f32x4_t __attribute__((ext_vector_type(4)));

// pack two floats to bf16x2 (round-up-at-halfway; 2 add + 1 perm)
__device__ __forceinline__ unsigned bpack(float hi, float lo) {
    unsigned uh = __float_as_uint(hi) + 0x8000u;
    unsigned ul = __float_as_uint(lo) + 0x8000u;
    return __builtin_amdgcn_perm(uh, ul, 0x07060302u);
}

__device__ __forceinline__ bf16_t to_bf16(float f) {
    union { float f; unsigned u; } x; x.f = f;
    unsigned r = (x.u + 0x7fffu + ((x.u >> 16) & 1u)) >> 16;
    union { unsigned short s; bf16_t b; } y; y.s = (unsigned short)r;
    return y.b;
}

// ---------------- w1 [512 k][256 n] f32 -> w1t [256 n][512 k] bf16 ------------
__global__ __launch_bounds__(256) void transpose_w1_kernel(
        const float* __restrict__ w1, bf16_t* __restrict__ w1t) {
    const int n = blockIdx.x;          // one output row per block
    const int t = threadIdx.x;
    #pragma unroll
    for (int u = 0; u < 2; ++u) {
        int k = t + u * 256;
        float v = w1[(size_t)k * DH_ + n];   // strided read (L2-shared lines)
        w1t[(size_t)n * DM_ + k] = to_bf16(v); // coalesced write
    }
}

// ---------------- MLP via MFMA: fused = relu(raw@w1+b1)@w2 + b2 --------------
// 256 blocks x 256 threads; block owns 16 rows, wave owns a 64-wide n-quarter.
__global__ __launch_bounds__(256) void mlp_kernel(
        const float* __restrict__ raw, const bf16_t* __restrict__ w1t,
        const float* __restrict__ b1, const float* __restrict__ w2,
        const float* __restrict__ b2, float* __restrict__ fused) {
    __shared__ bf16_t Rs[16][520];     // raw rows, bf16, padded stride
    __shared__ float part[4][16];
    const int t = threadIdx.x;
    const int m0 = blockIdx.x * 16;
    // stage 16 raw rows (16x512 f32) -> bf16 LDS
    #pragma unroll
    for (int u = 0; u < 8; ++u) {
        int idx = t + u * 256;
        int row = idx >> 7;            // 128 f32x4 per row
        int k = (idx & 127) << 2;
        f32x4_t v = *(const f32x4_t*)&raw[(size_t)(m0 + row) * DM_ + k];
        uint2 p;
        p.x = bpack(v[1], v[0]);
        p.y = bpack(v[3], v[2]);
        *(uint2*)&Rs[row][k] = p;
    }
    __syncthreads();
    const int wave = t >> 6;
    const int lane = t & 63;
    const int lrow = lane & 15;
    const int lgrp = lane >> 4;
    const int n0w = wave * 64;

    f32x4_t acc[4];
    #pragma unroll
    for (int nt = 0; nt < 4; ++nt) acc[nt] = (f32x4_t){0.f, 0.f, 0.f, 0.f};

    const bf16_t* wbase = w1t + (size_t)(n0w + lrow) * DM_ + lgrp * 8;
    #pragma unroll
    for (int s = 0; s < 16; ++s) {
        bf16x8_t a = *(const bf16x8_t*)&Rs[lrow][s * 32 + lgrp * 8];
        #pragma unroll
        for (int nt = 0; nt < 4; ++nt) {
            bf16x8_t b = *(const bf16x8_t*)(wbase + nt * 16 * DM_ + s * 32);
            acc[nt] = __builtin_amdgcn_mfma_f32_16x16x32_bf16(a, b, acc[nt], 0, 0, 0);
        }
    }
    // epilogue: relu + @w2, reduce over n
    float rowpart[4] = {0.f, 0.f, 0.f, 0.f};
    #pragma unroll
    for (int nt = 0; nt < 4; ++nt) {
        int n = n0w + nt * 16 + lrow;
        float b1v = b1[n];
        float w2v = w2[n];
        #pragma unroll
        for (int r = 0; r < 4; ++r) {
            float h = acc[nt][r] + b1v;
            h = h > 0.f ? h : 0.f;
            rowpart[r] += h * w2v;
        }
    }
    #pragma unroll
    for (int r = 0; r < 4; ++r) {
        float v = rowpart[r];
        v += __shfl_xor(v, 1);
        v += __shfl_xor(v, 2);
        v += __shfl_xor(v, 4);
        v += __shfl_xor(v, 8);
        if (lrow == 0) part[wave][lgrp * 4 + r] = v;
    }
    __syncthreads();
    if (t < 16)
        fused[m0 + t] = part[0][t] + part[1][t] + part[2][t] + part[3][t] + b2[0];
}

// ---------------- momentum ----------------------------------------------------
__global__ __launch_bounds__(256) void momentum_kernel(
        const float* __restrict__ fused, float* __restrict__ mom) {
    int i = blockIdx.x * 256 + threadIdx.x;
    if (i < B_ * L_) {
        int l = i & (L_ - 1);
        mom[i] = (l == 0) ? 0.f : fused[i] - fused[i - 1];
    }
}

// ---------------- flash attention, no-max softmax, pipelined staging ----------
struct TileRegs { f32x4_t k[4]; float v[16]; float m; };

__global__ __launch_bounds__(256) void attn_kernel(
        const float* __restrict__ Q, const float* __restrict__ K,
        const float* __restrict__ V, const float* __restrict__ mom,
        const float* __restrict__ alpha_trend, float* __restrict__ out) {
    __shared__ bf16_t Ks[64][72];           // [s][e]
    __shared__ bf16_t Vt[64][72];           // [d][s]
    __shared__ unsigned short Ps[4][16][68]; // per-wave P scratch [q][s], bf16 bits
    __shared__ float moms[64];

    const int bid  = blockIdx.x;
    const int bh   = bid & 31;
    const int qt   = 31 - (bid >> 5);       // heavy diagonals first
    const int h    = bh & 15;
    const int b    = bh >> 4;
    const int q0   = qt << 6;
    const int tid  = threadIdx.x;
    const int wave = tid >> 6;
    const int lane = tid & 63;
    const int lrow = lane & 15;
    const int lgrp = lane >> 4;

    const float c1     = 0.18033688f;       // 0.125 * log2(e)
    const float ascale2 = alpha_trend[h] * c1;
    const size_t bl    = (size_t)b * L_;
    const int qw0      = q0 + wave * 16;

    const float* Kb   = K + ((bl)*H_ + h) * E_;
    const float* Vb   = V + ((bl)*H_ + h) * D_;
    const float* momp = mom + bl;

    // staging thread mapping
    const int krow = tid >> 4;              // +u*16
    const int ke0  = (tid & 15) << 2;
    const int vd   = tid & 63;
    const int vsb  = tid >> 6;

    // Q fragments, prescaled by c1 (RNE, once)
    bf16x8_t a_lo, a_hi;
    {
        const float* qp = Q + ((bl + qw0 + lrow) * H_ + h) * E_ + lgrp * 8;
        f32x4_t v0 = *(const f32x4_t*)(qp);
        f32x4_t v1 = *(const f32x4_t*)(qp + 4);
        f32x4_t v2 = *(const f32x4_t*)(qp + 32);
        f32x4_t v3 = *(const f32x4_t*)(qp + 36);
        #pragma unroll
        for (int k = 0; k < 4; ++k) {
            a_lo[k]     = to_bf16(v0[k] * c1);
            a_lo[4 + k] = to_bf16(v1[k] * c1);
            a_hi[k]     = to_bf16(v2[k] * c1);
            a_hi[4 + k] = to_bf16(v3[k] * c1);
        }
    }
    float mq[4];
    #pragma unroll
    for (int r = 0; r < 4; ++r) mq[r] = momp[qw0 + lgrp * 4 + r];

    f32x4_t Oacc[4];
    #pragma unroll
    for (int c = 0; c < 4; ++c) Oacc[c] = (f32x4_t){0.f, 0.f, 0.f, 0.f};
    float rowsum[4] = {0.f, 0.f, 0.f, 0.f};

    // prologue: preload tile 0 into registers
    TileRegs tr;
    {
        #pragma unroll
        for (int u = 0; u < 4; ++u)
            tr.k[u] = *(const f32x4_t*)&Kb[(krow + u * 16) * (H_ * E_) + ke0];
        #pragma unroll
        for (int j = 0; j < 16; ++j)
            tr.v[j] = Vb[(vsb * 16 + j) * (H_ * D_) + vd];
        tr.m = (tid < 64) ? momp[tid] : 0.f;
    }

    for (int st = 0; st <= qt; ++st) {
        __syncthreads();   // previous compute done reading LDS
        // registers -> LDS (bf16 packed)
        #pragma unroll
        for (int u = 0; u < 4; ++u) {
            uint2 p;
            p.x = bpack(tr.k[u][1], tr.k[u][0]);
            p.y = bpack(tr.k[u][3], tr.k[u][2]);
            *(uint2*)&Ks[krow + u * 16][ke0] = p;
        }
        #pragma unroll
        for (int u = 0; u < 4; ++u) {
            uint2 p;
            p.x = bpack(tr.v[u * 4 + 1], tr.v[u * 4 + 0]);
            p.y = bpack(tr.v[u * 4 + 3], tr.v[u * 4 + 2]);
            *(uint2*)&Vt[vd][vsb * 16 + u * 4] = p;
        }
        if (tid < 64) moms[tid] = tr.m;
        __syncthreads();   // stage visible

        // issue next tile's global loads (latency hidden behind compute)
        if (st < qt) {
            const int s0n = (st + 1) << 6;
            #pragma unroll
            for (int u = 0; u < 4; ++u)
                tr.k[u] = *(const f32x4_t*)&Kb[(s0n + krow + u * 16) * (H_ * E_) + ke0];
            #pragma unroll
            for (int j = 0; j < 16; ++j)
                tr.v[j] = Vb[(s0n + vsb * 16 + j) * (H_ * D_) + vd];
            tr.m = (tid < 64) ? momp[s0n + tid] : 0.f;
        }

        // S = Q K^T (already in log2 domain via prescale)
        f32x4_t Sacc[4];
        #pragma unroll
        for (int c = 0; c < 4; ++c) Sacc[c] = (f32x4_t){0.f, 0.f, 0.f, 0.f};
        #pragma unroll
        for (int c = 0; c < 4; ++c) {
            bf16x8_t b_lo = *(const bf16x8_t*)&Ks[c * 16 + lrow][lgrp * 8];
            bf16x8_t b_hi = *(const bf16x8_t*)&Ks[c * 16 + lrow][32 + lgrp * 8];
            Sacc[c] = __builtin_amdgcn_mfma_f32_16x16x32_bf16(a_lo, b_lo, Sacc[c], 0, 0, 0);
            Sacc[c] = __builtin_amdgcn_mfma_f32_16x16x32_bf16(a_hi, b_hi, Sacc[c], 0, 0, 0);
        }

        // P = exp2(S - ascale2*|dm|), no max subtraction needed
        float rowe[4][4];
        #pragma unroll
        for (int c = 0; c < 4; ++c) {
            float ms = moms[c * 16 + lrow];
            #pragma unroll
            for (int r = 0; r < 4; ++r) {
                float arg = Sacc[c][r] - ascale2 * fabsf(mq[r] - ms);
                rowe[c][r] = __builtin_amdgcn_exp2f(arg);
            }
        }
        if (st == qt) {   // causal mask on diagonal macro-tile
            const int s0 = st << 6;
            #pragma unroll
            for (int c = 0; c < 4; ++c) {
                int sg = s0 + c * 16 + lrow;
                #pragma unroll
                for (int r = 0; r < 4; ++r)
                    if (sg > qw0 + lgrp * 4 + r) rowe[c][r] = 0.f;
            }
        }
        // store bf16 P (wave-private scratch; no barrier needed) + row sums
        unsigned short* Psw = &Ps[wave][0][0];
        #pragma unroll
        for (int c = 0; c < 4; ++c) {
            #pragma unroll
            for (int r = 0; r < 4; ++r) {
                unsigned u = (__float_as_uint(rowe[c][r]) + 0x8000u) & 0xffff0000u;
                Psw[(lgrp * 4 + r) * 68 + c * 16 + lrow] = (unsigned short)(u >> 16);
                rowsum[r] += __uint_as_float(u);
            }
        }

        // O += P V
        #pragma unroll
        for (int hh = 0; hh < 2; ++hh) {
            union { uint2 u2[2]; bf16x8_t v; } ab;
            ab.u2[0] = *(const uint2*)&Psw[lrow * 68 + hh * 32 + lgrp * 8];
            ab.u2[1] = *(const uint2*)&Psw[lrow * 68 + hh * 32 + lgrp * 8 + 4];
            #pragma unroll
            for (int c2 = 0; c2 < 4; ++c2) {
                bf16x8_t bv = *(const bf16x8_t*)&Vt[c2 * 16 + lrow][hh * 32 + lgrp * 8];
                Oacc[c2] = __builtin_amdgcn_mfma_f32_16x16x32_bf16(ab.v, bv, Oacc[c2], 0, 0, 0);
            }
        }
    }

    // epilogue: reduce row sums across the 16 s-lanes, normalize, store
    #pragma unroll
    for (int r = 0; r < 4; ++r) {
        float rs = rowsum[r];
        rs += __shfl_xor(rs, 1);
        rs += __shfl_xor(rs, 2);
        rs += __shfl_xor(rs, 4);
        rs += __shfl_xor(rs, 8);
        float inv = 1.f / rs;
        size_t orow = ((bl + qw0 + lgrp * 4 + r) * H_ + h) * D_;
        #pragma unroll
        for (int c = 0; c < 4; ++c)
            out[orow + c * 16 + lrow] = Oacc[c][r] * inv;
    }
}

extern "C" void kernel_launch(void* const* d_in, const int* in_sizes, int n_in,
                              void* d_out, int out_size, void* d_ws, size_t ws_size,
                              hipStream_t stream) {
    const float* Q     = (const float*)d_in[0];
    const float* K     = (const float*)d_in[1];
    const float* V     = (const float*)d_in[2];
    const float* raw   = (const float*)d_in[3];
    const float* w1    = (const float*)d_in[4];
    const float* b1    = (const float*)d_in[5];
    const float* w2    = (const float*)d_in[6];
    const float* b2    = (const float*)d_in[7];
    const float* alpha = (const float*)d_in[8];
    float* out = (float*)d_out;

    float* fused = (float*)d_ws;                  // B*L floats
    float* mom   = fused + B_ * L_;               // B*L floats
    bf16_t* w1t  = (bf16_t*)(mom + B_ * L_);      // 256*512 bf16 (256 KB)

    transpose_w1_kernel<<<DH_, 256, 0, stream>>>(w1, w1t);
    mlp_kernel<<<B_ * L_ / 16, 256, 0, stream>>>(raw, w1t, b1, w2, b2, fused);
    momentum_kernel<<<(B_ * L_ + 255) / 256, 256, 0, stream>>>(fused, mom);
    attn_kernel<<<B_ * H_ * (L_ / 64), 256, 0, stream>>>(Q, K, V, mom, alpha, out);
}